// Round 10
// baseline (382.941 us; speedup 1.0000x reference)
//
#include <hip/hip_runtime.h>
#include <math.h>

#define N_NODES 50000
#define N_PAD   50048          // padded to multiple of 128 for GEMM tiles
#define N_EDGES 800000
#define IN_F 128
#define H_F 256
#define OUT_F 10
#define N_G 128
#define POOL_CHUNK 128
#define POOL_MAXCHUNKS 16
#define NCHUNKS 196            // ceil(N_NODES/256)

typedef __attribute__((ext_vector_type(4))) float f32x4;
typedef __attribute__((ext_vector_type(2))) float f32x2;
typedef unsigned char u8;

// ---- fp8 e4m3 (OCP) helpers: HW packed converts (imm word-select) ----
__device__ inline f32x2 fp8x2_f32_lo(unsigned int v) {
    return __builtin_amdgcn_cvt_pk_f32_fp8(v, false);
}
__device__ inline f32x2 fp8x2_f32_hi(unsigned int v) {
    return __builtin_amdgcn_cvt_pk_f32_fp8(v, true);
}
__device__ inline unsigned int f32_fp8x2_lo(float a, float b, unsigned int old) {
    return __builtin_amdgcn_cvt_pk_fp8_f32(a, b, old, false);
}
__device__ inline unsigned int f32_fp8x2_hi(float a, float b, unsigned int old) {
    return __builtin_amdgcn_cvt_pk_fp8_f32(a, b, old, true);
}
__device__ inline u8 f32_fp8(float a) {
    return (u8)(f32_fp8x2_lo(a, a, 0u) & 0xff);
}
// ---- bf16 helpers (packed CSR weight) ----
__device__ inline ushort f2bf(float x) {
    union { float f; unsigned int u; } v; v.f = x;
    unsigned int r = v.u + 0x7fff + ((v.u >> 16) & 1);
    return (ushort)(r >> 16);
}
__device__ inline float bf2f(ushort u) {
    union { unsigned int u; float f; } v; v.u = ((unsigned int)u) << 16; return v.f;
}

// async global->LDS, 16 B per lane; lds dest = wave-uniform base + lane*16
__device__ inline void gl2lds16(const void* g, void* l) {
    __builtin_amdgcn_global_load_lds(
        (const __attribute__((address_space(1))) unsigned int*)g,
        (__attribute__((address_space(3))) unsigned int*)l,
        16, 0, 0);
}

// ------------------------------------------------------------------
// Mega-fused prep (block roles by blockIdx range)
// histogram role: 8 edges/thread (strided by 256 within a 2048-edge block
// chunk) -> 8 independent atomic chains in flight per thread.
// ------------------------------------------------------------------
#define PREP_CE   391                    // ceil(800000 / 2048)
#define PREP_CV   (PREP_CE + 6250)
#define PREP_T0   (PREP_CV + 128)
#define PREP_T1   (PREP_T0 + 256)
#define PREP_T2   (PREP_T1 + 256)
#define PREP_GS   (PREP_T2 + NCHUNKS)

__global__ __launch_bounds__(256) void prep_kernel(
    const int* __restrict__ col, int* __restrict__ counts,
    const float* __restrict__ x, u8* __restrict__ xb,
    const float* __restrict__ W0, u8* __restrict__ W0t,
    const float* __restrict__ W1, u8* __restrict__ W1t,
    const float* __restrict__ W2, u8* __restrict__ W2t,
    const int* __restrict__ batch, int* __restrict__ gstart) {
    int b = blockIdx.x;
    int tid = threadIdx.x;
    if (b < PREP_CE) {
        int base = b * 2048 + tid;
        int c[8];
        #pragma unroll
        for (int u = 0; u < 8; ++u) {
            int e = base + u * 256;
            c[u] = (e < N_EDGES) ? col[e] : -1;
        }
        #pragma unroll
        for (int u = 0; u < 8; ++u)
            if (c[u] >= 0) atomicAdd(&counts[c[u]], 1);
    } else if (b < PREP_CV) {
        int i = (b - PREP_CE) * 256 + tid;      // < 1,600,000 exactly
        float4 v = *(const float4*)(x + (size_t)i * 4);
        unsigned int p = f32_fp8x2_lo(v.x, v.y, 0u);
        p = f32_fp8x2_hi(v.z, v.w, p);
        *(unsigned int*)(xb + (size_t)i * 4) = p;
    } else if (b < PREP_T0) {
        int idx = (b - PREP_CV) * 256 + tid;    // < 32768
        int k = idx >> 8, nn = idx & 255;       // K=128, Nc=256
        W0t[nn * IN_F + k] = f32_fp8(W0[idx]);
    } else if (b < PREP_T1) {
        int idx = (b - PREP_T0) * 256 + tid;    // < 65536
        int k = idx >> 8, nn = idx & 255;
        W1t[nn * H_F + k] = f32_fp8(W1[idx]);
    } else if (b < PREP_T2) {
        int idx = (b - PREP_T1) * 256 + tid;
        int k = idx >> 8, nn = idx & 255;
        W2t[nn * H_F + k] = f32_fp8(W2[idx]);
    } else {
        int i = (b - PREP_T2) * 256 + tid;
        if (i >= N_NODES) return;
        int bb = batch[i];
        if (i == 0) {
            for (int g = 0; g <= bb; ++g) gstart[g] = 0;
        } else {
            int p = batch[i - 1];
            if (p != bb) { for (int g = p + 1; g <= bb; ++g) gstart[g] = i; }
        }
        if (i == N_NODES - 1) {
            for (int g = bb + 1; g <= N_G; ++g) gstart[g] = N_NODES;
        }
    }
}

// ------------------------------------------------------------------
// per-chunk sums of counts (196 blocks)
// ------------------------------------------------------------------
__global__ __launch_bounds__(256) void chunk_reduce(const int* __restrict__ counts,
                                                    int* __restrict__ csum, int n) {
    int i = blockIdx.x * 256 + threadIdx.x;
    int v = (i < n) ? counts[i] : 0;
    #pragma unroll
    for (int off = 32; off; off >>= 1) v += __shfl_down(v, off);
    __shared__ int ws[4];
    if ((threadIdx.x & 63) == 0) ws[threadIdx.x >> 6] = v;
    __syncthreads();
    if (threadIdx.x == 0) csum[blockIdx.x] = ws[0] + ws[1] + ws[2] + ws[3];
}

// ------------------------------------------------------------------
// scan + dinv + cursor-zero, fully parallel (196 blocks)
// ------------------------------------------------------------------
__global__ __launch_bounds__(256) void scan_dinv_kernel(const int* __restrict__ counts,
                                                        const int* __restrict__ csum,
                                                        int* __restrict__ offsets,
                                                        float* __restrict__ dinv,
                                                        int* __restrict__ cursor, int n) {
    int tid = threadIdx.x;
    int lane = tid & 63, wid = tid >> 6;
    int cv = (tid < NCHUNKS) ? csum[tid] : 0;
    int xc = cv;
    #pragma unroll
    for (int off = 1; off < 64; off <<= 1) {
        int t = __shfl_up(xc, off);
        if (lane >= off) xc += t;
    }
    __shared__ int cw[4], cpre[4];
    __shared__ int cexcl[256];
    if (lane == 63) cw[wid] = xc;
    __syncthreads();
    if (tid == 0) { int s = 0; for (int k = 0; k < 4; ++k) { cpre[k] = s; s += cw[k]; } }
    __syncthreads();
    cexcl[tid] = cpre[wid] + xc - cv;
    __syncthreads();
    int base = cexcl[blockIdx.x];
    int i = blockIdx.x * 256 + tid;
    int v = (i < n) ? counts[i] : 0;
    int x = v;
    #pragma unroll
    for (int off = 1; off < 64; off <<= 1) {
        int t = __shfl_up(x, off);
        if (lane >= off) x += t;
    }
    __shared__ int wsum[4], wpre[4];
    if (lane == 63) wsum[wid] = x;
    __syncthreads();
    if (tid == 0) { int s = 0; for (int k = 0; k < 4; ++k) { wpre[k] = s; s += wsum[k]; } }
    __syncthreads();
    if (i < n) {
        offsets[i] = base + wpre[wid] + x - v;   // exclusive
        dinv[i] = rsqrtf((float)(v + 1));
        cursor[i] = 0;
    }
    if (blockIdx.x == 0 && tid == 0) offsets[n] = N_EDGES;
}

// Packed CSR: entry = src (16 bits, N_NODES<65536) | bf16 weight << 16.
// weight = dinv[dst]*dinv[src]. 8 edges/thread for atomic-chain ILP.
__global__ __launch_bounds__(256) void fill_csr_kernel(const int* __restrict__ row,
                                                       const int* __restrict__ col,
                                                       const int* __restrict__ offsets,
                                                       int* __restrict__ cursor,
                                                       const float* __restrict__ dinv,
                                                       unsigned int* __restrict__ csr_ew) {
    int base = blockIdx.x * 2048 + threadIdx.x;
    int c[8], r[8];
    #pragma unroll
    for (int u = 0; u < 8; ++u) {
        int e = base + u * 256;
        if (e < N_EDGES) { c[u] = col[e]; r[u] = row[e]; }
        else             { c[u] = -1; r[u] = 0; }
    }
    float dc[8], dr[8];
    int ofs[8];
    #pragma unroll
    for (int u = 0; u < 8; ++u) {
        if (c[u] >= 0) { dc[u] = dinv[c[u]]; dr[u] = dinv[r[u]]; ofs[u] = offsets[c[u]]; }
    }
    int p[8];
    #pragma unroll
    for (int u = 0; u < 8; ++u)
        if (c[u] >= 0) p[u] = atomicAdd(&cursor[c[u]], 1);
    #pragma unroll
    for (int u = 0; u < 8; ++u) {
        if (c[u] >= 0) {
            float w = dc[u] * dr[u];
            csr_ew[ofs[u] + p[u]] = (unsigned int)r[u] | ((unsigned int)f2bf(w) << 16);
        }
    }
}

// ------------------------------------------------------------------
// fp8 MFMA GEMM: C[N_PAD x 256] = A[N_PAD x K] @ Bt^T   (Bt is [256][K], fp8)
// 128x128 tile / block (4 waves 2x2), BK=128: four 4 KB k-planes per operand
// per stage ([128 rows][32 k-bytes] each), async global_load_lds staging.
// ------------------------------------------------------------------
template <int K, bool RELU>
__global__ __launch_bounds__(256) void gemm_fp8(const u8* __restrict__ A,
                                                const u8* __restrict__ Bt,
                                                u8* __restrict__ C) {
    __shared__ u8 As[4 * 4096];
    __shared__ u8 Bs[4 * 4096];
    int tid = threadIdx.x;
    int lane = tid & 63;
    int w = tid >> 6;
    int wm = w & 1, wn = w >> 1;
    int l16 = lane & 15, quad = lane >> 4;
    int row0 = blockIdx.x * 128;
    int col0 = blockIdx.y * 128;
    f32x4 acc[4][4] = {};

    int sr = tid >> 1;             // staging row 0..127
    int sh = (tid & 1) * 16;       // half-plane-row byte offset
    const u8* ga = A + (size_t)(row0 + sr) * K + sh;
    const u8* gb = Bt + (size_t)(col0 + sr) * K + sh;

    #pragma unroll
    for (int k0 = 0; k0 < K; k0 += 128) {
        if (k0) __syncthreads();
        #pragma unroll
        for (int q = 0; q < 4; ++q) {   // k-plane within stage
            gl2lds16(ga + k0 + q * 32, As + q * 4096 + w * 1024);
            gl2lds16(gb + k0 + q * 32, Bs + q * 4096 + w * 1024);
        }
        __syncthreads();
        #pragma unroll
        for (int h = 0; h < 4; ++h) {
            long af[4], bfr[4];
            #pragma unroll
            for (int i = 0; i < 4; ++i)
                af[i] = *(const long*)&As[h * 4096 + (wm * 64 + i * 16 + l16) * 32 + quad * 8];
            #pragma unroll
            for (int j = 0; j < 4; ++j)
                bfr[j] = *(const long*)&Bs[h * 4096 + (wn * 64 + j * 16 + l16) * 32 + quad * 8];
            #pragma unroll
            for (int i = 0; i < 4; ++i)
                #pragma unroll
                for (int j = 0; j < 4; ++j)
                    acc[i][j] = __builtin_amdgcn_mfma_f32_16x16x32_fp8_fp8(af[i], bfr[j], acc[i][j], 0, 0, 0);
        }
    }
    // epilogue: C/D layout col=lane&15, row=quad*4+reg (dtype-independent)
    #pragma unroll
    for (int i = 0; i < 4; ++i) {
        int rowb = row0 + wm * 64 + i * 16 + quad * 4;
        #pragma unroll
        for (int r = 0; r < 4; ++r) {
            int grow = rowb + r;
            #pragma unroll
            for (int j = 0; j < 4; ++j) {
                int gcol = col0 + wn * 64 + j * 16 + l16;
                float v = acc[i][j][r];
                if (RELU) v = fmaxf(v, 0.f);
                C[(size_t)grow * H_F + gcol] = f32_fp8(v);
            }
        }
    }
}

// ------------------------------------------------------------------
// GCN aggregation, 128-ch fp8 (layer-0, pre-GEMM), NO relu.
// ------------------------------------------------------------------
__global__ __launch_bounds__(256) void aggregate128(const u8* __restrict__ hw,
                                                    const float* __restrict__ dinv,
                                                    const int* __restrict__ offsets,
                                                    const unsigned int* __restrict__ csr_ew,
                                                    u8* __restrict__ hout) {
    int w = threadIdx.x >> 6;
    int lane = threadIdx.x & 63;
    int i = blockIdx.x * 4 + w;
    if (i >= N_NODES) return;
    float di = dinv[i];
    const u8* base = hw + (size_t)lane * 2;
    unsigned int su = *(const unsigned short*)(base + (size_t)i * IN_F);
    f32x2 sv = fp8x2_f32_lo(su);
    float s = di * di;
    float a0 = s * sv.x, a1 = s * sv.y;
    int t = offsets[i], end = offsets[i + 1];
    for (; t + 8 <= end; t += 8) {
        unsigned int e[8];
        unsigned int v[8];
        #pragma unroll
        for (int u = 0; u < 8; ++u) e[u] = csr_ew[t + u];
        #pragma unroll
        for (int u = 0; u < 8; ++u)
            v[u] = *(const unsigned short*)(base + (size_t)(e[u] & 0xffff) * IN_F);
        #pragma unroll
        for (int u = 0; u < 8; ++u) {
            float wq = bf2f((ushort)(e[u] >> 16));
            f32x2 f = fp8x2_f32_lo(v[u]);
            a0 += wq * f.x; a1 += wq * f.y;
        }
    }
    for (; t < end; ++t) {
        unsigned int e0 = csr_ew[t];
        unsigned int v0 = *(const unsigned short*)(base + (size_t)(e0 & 0xffff) * IN_F);
        float wq = bf2f((ushort)(e0 >> 16));
        f32x2 f = fp8x2_f32_lo(v0);
        a0 += wq * f.x; a1 += wq * f.y;
    }
    unsigned int o = f32_fp8x2_lo(a0, a1, 0u);
    *(unsigned short*)(hout + (size_t)i * IN_F + lane * 2) = (unsigned short)(o & 0xffff);
}

// ------------------------------------------------------------------
// GCN aggregation, 256-ch fp8, + relu. wave per node, lane = 4 channels.
// ------------------------------------------------------------------
__global__ __launch_bounds__(256) void aggregate256(const u8* __restrict__ hw,
                                                    const float* __restrict__ dinv,
                                                    const int* __restrict__ offsets,
                                                    const unsigned int* __restrict__ csr_ew,
                                                    u8* __restrict__ hout) {
    int w = threadIdx.x >> 6;
    int lane = threadIdx.x & 63;
    int i = blockIdx.x * 4 + w;
    if (i >= N_NODES) return;
    float di = dinv[i];
    const u8* base = hw + (size_t)lane * 4;
    unsigned int su = *(const unsigned int*)(base + (size_t)i * H_F);
    f32x2 slo = fp8x2_f32_lo(su), shi = fp8x2_f32_hi(su);
    float s = di * di;
    float a0 = s * slo.x, a1 = s * slo.y, a2 = s * shi.x, a3 = s * shi.y;
    int t = offsets[i], end = offsets[i + 1];
    for (; t + 8 <= end; t += 8) {
        unsigned int e[8];
        unsigned int v[8];
        #pragma unroll
        for (int u = 0; u < 8; ++u) e[u] = csr_ew[t + u];
        #pragma unroll
        for (int u = 0; u < 8; ++u)
            v[u] = *(const unsigned int*)(base + (size_t)(e[u] & 0xffff) * H_F);
        #pragma unroll
        for (int u = 0; u < 8; ++u) {
            float wq = bf2f((ushort)(e[u] >> 16));
            f32x2 lo = fp8x2_f32_lo(v[u]), hi = fp8x2_f32_hi(v[u]);
            a0 += wq * lo.x; a1 += wq * lo.y;
            a2 += wq * hi.x; a3 += wq * hi.y;
        }
    }
    for (; t < end; ++t) {
        unsigned int e0 = csr_ew[t];
        unsigned int v0 = *(const unsigned int*)(base + (size_t)(e0 & 0xffff) * H_F);
        float wq = bf2f((ushort)(e0 >> 16));
        f32x2 lo = fp8x2_f32_lo(v0), hi = fp8x2_f32_hi(v0);
        a0 += wq * lo.x; a1 += wq * lo.y;
        a2 += wq * hi.x; a3 += wq * hi.y;
    }
    unsigned int o = f32_fp8x2_lo(fmaxf(a0, 0.f), fmaxf(a1, 0.f), 0u);
    o = f32_fp8x2_hi(fmaxf(a2, 0.f), fmaxf(a3, 0.f), o);
    *(unsigned int*)(hout + (size_t)i * H_F + lane * 4) = o;
}

// ------------------------------------------------------------------
// Pool: (graph, node-chunk) blocks, fp32 atomic partial sums. fp8 input.
// ------------------------------------------------------------------
__global__ __launch_bounds__(256) void pool_part(const u8* __restrict__ h,
                                                 const int* __restrict__ gstart,
                                                 float* __restrict__ pooled) {
    int g = blockIdx.x;
    int s = gstart[g] + blockIdx.y * POOL_CHUNK;
    int e = min(gstart[g + 1], s + POOL_CHUNK);
    if (s >= e) return;
    int c = threadIdx.x;
    float sum = 0.f;
    for (int i = s; i < e; ++i) {
        f32x2 f = fp8x2_f32_lo((unsigned int)h[(size_t)i * H_F + c]);
        sum += f.x;
    }
    atomicAdd(&pooled[g * H_F + c], sum);
}

// ------------------------------------------------------------------
// Fused MLP head (all fp32)
// ------------------------------------------------------------------
__global__ __launch_bounds__(256) void mlp_head_kernel(const float* __restrict__ pooled,
                                                       const int* __restrict__ gstart,
                                                       const float* __restrict__ Wm1,
                                                       const float* __restrict__ bm1,
                                                       const float* __restrict__ Wm2,
                                                       const float* __restrict__ bm2,
                                                       float* __restrict__ out) {
    __shared__ float p[H_F];
    __shared__ float h[H_F];
    __shared__ float lastv[OUT_F];
    __shared__ float stats[2];
    int g = blockIdx.x, j = threadIdx.x;
    int cnt = gstart[g + 1] - gstart[g];
    p[j] = pooled[g * H_F + j] / (float)max(cnt, 1);
    __syncthreads();
    float acc = bm1[j];
    for (int k = 0; k < H_F; ++k) acc += p[k] * Wm1[k * H_F + j];
    h[j] = fmaxf(acc, 0.f);
    __syncthreads();
    if (j < OUT_F) {
        float a = bm2[j];
        for (int k = 0; k < H_F; ++k) a += h[k] * Wm2[k * OUT_F + j];
        lastv[j] = a;
    }
    __syncthreads();
    if (j == 0) {
        float m = -1e30f;
        for (int o = 0; o < OUT_F; ++o) m = fmaxf(m, lastv[o]);
        float s = 0.f;
        for (int o = 0; o < OUT_F; ++o) s += expf(lastv[o] - m);
        stats[0] = m; stats[1] = logf(s);
    }
    __syncthreads();
    if (j < OUT_F) {
        float v = lastv[j];
        out[g * OUT_F + j] = v - stats[0] - stats[1];
        out[(size_t)N_G * OUT_F + g * OUT_F + j] = 1.f / (1.f + expf(-v));
        out[(size_t)2 * N_G * OUT_F + g * OUT_F + j] = v;
    }
}

// ------------------------------------------------------------------
extern "C" void kernel_launch(void* const* d_in, const int* in_sizes, int n_in,
                              void* d_out, int out_size, void* d_ws, size_t ws_size,
                              hipStream_t stream) {
    const float* x   = (const float*)d_in[0];
    const int* edge_index = (const int*)d_in[1];
    const int* batch = (const int*)d_in[3];
    const float* W0  = (const float*)d_in[4];
    const float* W1  = (const float*)d_in[5];
    const float* W2  = (const float*)d_in[6];
    const float* Wm1 = (const float*)d_in[7];
    const float* bm1 = (const float*)d_in[8];
    const float* Wm2 = (const float*)d_in[9];
    const float* bm2 = (const float*)d_in[10];
    float* out = (float*)d_out;

    char* ws = (char*)d_ws;
    size_t off = 0;
    auto alloc = [&](size_t bytes) -> void* {
        void* p = ws + off; off += (bytes + 255) & ~(size_t)255; return p;
    };
    u8* xb       = (u8*)alloc((size_t)N_PAD * IN_F);
    u8* bufA     = (u8*)alloc((size_t)N_PAD * H_F);
    u8* bufB     = (u8*)alloc((size_t)N_PAD * H_F);
    u8* t0       = (u8*)alloc((size_t)N_PAD * IN_F);
    u8* W0t      = (u8*)alloc((size_t)H_F * IN_F);
    u8* W1t      = (u8*)alloc((size_t)H_F * H_F);
    u8* W2t      = (u8*)alloc((size_t)H_F * H_F);
    float* dinv    = (float*)alloc((size_t)N_NODES * 4);
    int*   counts  = (int*)alloc((size_t)N_NODES * 4);
    int*   offsets = (int*)alloc((size_t)(N_NODES + 1) * 4);
    int*   cursor  = (int*)alloc((size_t)N_NODES * 4);
    unsigned int* csr_ew = (unsigned int*)alloc((size_t)N_EDGES * 4);
    int*   csum    = (int*)alloc((size_t)256 * 4);
    int*   gstart  = (int*)alloc((size_t)(N_G + 1) * 4);
    float* pooled  = (float*)alloc((size_t)N_G * H_F * 4);

    const int* row = edge_index;
    const int* col = edge_index + N_EDGES;

    hipMemsetAsync(counts, 0, (size_t)N_NODES * 4, stream);
    hipMemsetAsync(pooled, 0, (size_t)N_G * H_F * 4, stream);

    prep_kernel<<<PREP_GS, 256, 0, stream>>>(col, counts, x, xb,
                                             W0, W0t, W1, W1t, W2, W2t,
                                             batch, gstart);
    chunk_reduce<<<NCHUNKS, 256, 0, stream>>>(counts, csum, N_NODES);
    scan_dinv_kernel<<<NCHUNKS, 256, 0, stream>>>(counts, csum, offsets, dinv,
                                                  cursor, N_NODES);
    fill_csr_kernel<<<391, 256, 0, stream>>>(row, col, offsets, cursor, dinv, csr_ew);

    dim3 gg(N_PAD / 128, H_F / 128);
    int agg_blocks = (N_NODES + 3) / 4;
    // layer 0: aggregate-first (linear ops commute), relu in GEMM epilogue
    aggregate128<<<agg_blocks, 256, 0, stream>>>(xb, dinv, offsets, csr_ew, t0);
    gemm_fp8<IN_F, true><<<gg, 256, 0, stream>>>(t0, W0t, bufA);
    // layer 1
    gemm_fp8<H_F, false><<<gg, 256, 0, stream>>>(bufA, W1t, bufB);
    aggregate256<<<agg_blocks, 256, 0, stream>>>(bufB, dinv, offsets, csr_ew, bufA);
    // layer 2
    gemm_fp8<H_F, false><<<gg, 256, 0, stream>>>(bufA, W2t, bufB);
    aggregate256<<<agg_blocks, 256, 0, stream>>>(bufB, dinv, offsets, csr_ew, bufA);

    dim3 pg(N_G, POOL_MAXCHUNKS);
    pool_part<<<pg, 256, 0, stream>>>(bufA, gstart, pooled);
    mlp_head_kernel<<<N_G, 256, 0, stream>>>(pooled, gstart, Wm1, bm1, Wm2, bm2, out);
}

// Round 11
// 351.758 us; speedup vs baseline: 1.0887x; 1.0887x over previous
//
#include <hip/hip_runtime.h>
#include <math.h>

#define N_NODES 50000
#define N_PAD   50048          // padded to multiple of 128 for GEMM tiles
#define N_EDGES 800000
#define IN_F 128
#define H_F 256
#define OUT_F 10
#define N_G 128
#define POOL_CHUNK 128
#define POOL_MAXCHUNKS 16
#define NCHUNKS 196            // ceil(N_NODES/256)

typedef __attribute__((ext_vector_type(4))) float f32x4;
typedef __attribute__((ext_vector_type(2))) float f32x2;
typedef unsigned char u8;

// ---- fp8 e4m3 (OCP) helpers: HW packed converts (imm word-select) ----
__device__ inline f32x2 fp8x2_f32_lo(unsigned int v) {
    return __builtin_amdgcn_cvt_pk_f32_fp8(v, false);
}
__device__ inline f32x2 fp8x2_f32_hi(unsigned int v) {
    return __builtin_amdgcn_cvt_pk_f32_fp8(v, true);
}
__device__ inline unsigned int f32_fp8x2_lo(float a, float b, unsigned int old) {
    return __builtin_amdgcn_cvt_pk_fp8_f32(a, b, old, false);
}
__device__ inline unsigned int f32_fp8x2_hi(float a, float b, unsigned int old) {
    return __builtin_amdgcn_cvt_pk_fp8_f32(a, b, old, true);
}
__device__ inline u8 f32_fp8(float a) {
    return (u8)(f32_fp8x2_lo(a, a, 0u) & 0xff);
}
// ---- bf16 helpers (packed CSR weight) ----
__device__ inline ushort f2bf(float x) {
    union { float f; unsigned int u; } v; v.f = x;
    unsigned int r = v.u + 0x7fff + ((v.u >> 16) & 1);
    return (ushort)(r >> 16);
}
__device__ inline float bf2f(ushort u) {
    union { unsigned int u; float f; } v; v.u = ((unsigned int)u) << 16; return v.f;
}

// async global->LDS, 16 B per lane; lds dest = wave-uniform base + lane*16
__device__ inline void gl2lds16(const void* g, void* l) {
    __builtin_amdgcn_global_load_lds(
        (const __attribute__((address_space(1))) unsigned int*)g,
        (__attribute__((address_space(3))) unsigned int*)l,
        16, 0, 0);
}

// ------------------------------------------------------------------
// Mega-fused prep (block roles by blockIdx range)
// histogram role: 1 edge/thread (max TLP); the atomic's return value IS the
// edge's rank within its destination bucket -> store it for atomic-free CSR.
// ------------------------------------------------------------------
#define PREP_CE   3125
#define PREP_CV   (PREP_CE + 6250)
#define PREP_T0   (PREP_CV + 128)
#define PREP_T1   (PREP_T0 + 256)
#define PREP_T2   (PREP_T1 + 256)
#define PREP_GS   (PREP_T2 + NCHUNKS)

__global__ __launch_bounds__(256) void prep_kernel(
    const int* __restrict__ col, int* __restrict__ counts, int* __restrict__ rank,
    const float* __restrict__ x, u8* __restrict__ xb,
    const float* __restrict__ W0, u8* __restrict__ W0t,
    const float* __restrict__ W1, u8* __restrict__ W1t,
    const float* __restrict__ W2, u8* __restrict__ W2t,
    const int* __restrict__ batch, int* __restrict__ gstart) {
    int b = blockIdx.x;
    int tid = threadIdx.x;
    if (b < PREP_CE) {
        int e = b * 256 + tid;
        if (e < N_EDGES) rank[e] = atomicAdd(&counts[col[e]], 1);
    } else if (b < PREP_CV) {
        int i = (b - PREP_CE) * 256 + tid;      // < 1,600,000 exactly
        float4 v = *(const float4*)(x + (size_t)i * 4);
        unsigned int p = f32_fp8x2_lo(v.x, v.y, 0u);
        p = f32_fp8x2_hi(v.z, v.w, p);
        *(unsigned int*)(xb + (size_t)i * 4) = p;
    } else if (b < PREP_T0) {
        int idx = (b - PREP_CV) * 256 + tid;    // < 32768
        int k = idx >> 8, nn = idx & 255;       // K=128, Nc=256
        W0t[nn * IN_F + k] = f32_fp8(W0[idx]);
    } else if (b < PREP_T1) {
        int idx = (b - PREP_T0) * 256 + tid;    // < 65536
        int k = idx >> 8, nn = idx & 255;
        W1t[nn * H_F + k] = f32_fp8(W1[idx]);
    } else if (b < PREP_T2) {
        int idx = (b - PREP_T1) * 256 + tid;
        int k = idx >> 8, nn = idx & 255;
        W2t[nn * H_F + k] = f32_fp8(W2[idx]);
    } else {
        int i = (b - PREP_T2) * 256 + tid;
        if (i >= N_NODES) return;
        int bb = batch[i];
        if (i == 0) {
            for (int g = 0; g <= bb; ++g) gstart[g] = 0;
        } else {
            int p = batch[i - 1];
            if (p != bb) { for (int g = p + 1; g <= bb; ++g) gstart[g] = i; }
        }
        if (i == N_NODES - 1) {
            for (int g = bb + 1; g <= N_G; ++g) gstart[g] = N_NODES;
        }
    }
}

// ------------------------------------------------------------------
// per-chunk sums of counts (196 blocks)
// ------------------------------------------------------------------
__global__ __launch_bounds__(256) void chunk_reduce(const int* __restrict__ counts,
                                                    int* __restrict__ csum, int n) {
    int i = blockIdx.x * 256 + threadIdx.x;
    int v = (i < n) ? counts[i] : 0;
    #pragma unroll
    for (int off = 32; off; off >>= 1) v += __shfl_down(v, off);
    __shared__ int ws[4];
    if ((threadIdx.x & 63) == 0) ws[threadIdx.x >> 6] = v;
    __syncthreads();
    if (threadIdx.x == 0) csum[blockIdx.x] = ws[0] + ws[1] + ws[2] + ws[3];
}

// ------------------------------------------------------------------
// scan + dinv, fully parallel (196 blocks)
// ------------------------------------------------------------------
__global__ __launch_bounds__(256) void scan_dinv_kernel(const int* __restrict__ counts,
                                                        const int* __restrict__ csum,
                                                        int* __restrict__ offsets,
                                                        float* __restrict__ dinv, int n) {
    int tid = threadIdx.x;
    int lane = tid & 63, wid = tid >> 6;
    int cv = (tid < NCHUNKS) ? csum[tid] : 0;
    int xc = cv;
    #pragma unroll
    for (int off = 1; off < 64; off <<= 1) {
        int t = __shfl_up(xc, off);
        if (lane >= off) xc += t;
    }
    __shared__ int cw[4], cpre[4];
    __shared__ int cexcl[256];
    if (lane == 63) cw[wid] = xc;
    __syncthreads();
    if (tid == 0) { int s = 0; for (int k = 0; k < 4; ++k) { cpre[k] = s; s += cw[k]; } }
    __syncthreads();
    cexcl[tid] = cpre[wid] + xc - cv;
    __syncthreads();
    int base = cexcl[blockIdx.x];
    int i = blockIdx.x * 256 + tid;
    int v = (i < n) ? counts[i] : 0;
    int x = v;
    #pragma unroll
    for (int off = 1; off < 64; off <<= 1) {
        int t = __shfl_up(x, off);
        if (lane >= off) x += t;
    }
    __shared__ int wsum[4], wpre[4];
    if (lane == 63) wsum[wid] = x;
    __syncthreads();
    if (tid == 0) { int s = 0; for (int k = 0; k < 4; ++k) { wpre[k] = s; s += wsum[k]; } }
    __syncthreads();
    if (i < n) {
        offsets[i] = base + wpre[wid] + x - v;   // exclusive
        dinv[i] = rsqrtf((float)(v + 1));
    }
    if (blockIdx.x == 0 && tid == 0) offsets[n] = N_EDGES;
}

// Packed CSR: entry = src (16 bits, N_NODES<65536) | bf16 weight << 16.
// weight = dinv[dst]*dinv[src]. ATOMIC-FREE: slot = offsets[c] + rank[e],
// rank precomputed by prep's histogram atomic. 1 edge/thread, full TLP.
__global__ __launch_bounds__(256) void fill_csr_kernel(const int* __restrict__ row,
                                                       const int* __restrict__ col,
                                                       const int* __restrict__ offsets,
                                                       const int* __restrict__ rank,
                                                       const float* __restrict__ dinv,
                                                       unsigned int* __restrict__ csr_ew) {
    int e = blockIdx.x * 256 + threadIdx.x;
    if (e < N_EDGES) {
        int c = col[e];
        int r = row[e];
        int k = rank[e];
        float w = dinv[c] * dinv[r];
        csr_ew[offsets[c] + k] = (unsigned int)r | ((unsigned int)f2bf(w) << 16);
    }
}

// ------------------------------------------------------------------
// fp8 MFMA GEMM: C[N_PAD x 256] = A[N_PAD x K] @ Bt^T   (Bt is [256][K], fp8)
// 128x128 tile / block (4 waves 2x2), BK=128: four 4 KB k-planes per operand
// per stage ([128 rows][32 k-bytes] each), async global_load_lds staging.
// ------------------------------------------------------------------
template <int K, bool RELU>
__global__ __launch_bounds__(256) void gemm_fp8(const u8* __restrict__ A,
                                                const u8* __restrict__ Bt,
                                                u8* __restrict__ C) {
    __shared__ u8 As[4 * 4096];
    __shared__ u8 Bs[4 * 4096];
    int tid = threadIdx.x;
    int lane = tid & 63;
    int w = tid >> 6;
    int wm = w & 1, wn = w >> 1;
    int l16 = lane & 15, quad = lane >> 4;
    int row0 = blockIdx.x * 128;
    int col0 = blockIdx.y * 128;
    f32x4 acc[4][4] = {};

    int sr = tid >> 1;             // staging row 0..127
    int sh = (tid & 1) * 16;       // half-plane-row byte offset
    const u8* ga = A + (size_t)(row0 + sr) * K + sh;
    const u8* gb = Bt + (size_t)(col0 + sr) * K + sh;

    #pragma unroll
    for (int k0 = 0; k0 < K; k0 += 128) {
        if (k0) __syncthreads();
        #pragma unroll
        for (int q = 0; q < 4; ++q) {   // k-plane within stage
            gl2lds16(ga + k0 + q * 32, As + q * 4096 + w * 1024);
            gl2lds16(gb + k0 + q * 32, Bs + q * 4096 + w * 1024);
        }
        __syncthreads();
        #pragma unroll
        for (int h = 0; h < 4; ++h) {
            long af[4], bfr[4];
            #pragma unroll
            for (int i = 0; i < 4; ++i)
                af[i] = *(const long*)&As[h * 4096 + (wm * 64 + i * 16 + l16) * 32 + quad * 8];
            #pragma unroll
            for (int j = 0; j < 4; ++j)
                bfr[j] = *(const long*)&Bs[h * 4096 + (wn * 64 + j * 16 + l16) * 32 + quad * 8];
            #pragma unroll
            for (int i = 0; i < 4; ++i)
                #pragma unroll
                for (int j = 0; j < 4; ++j)
                    acc[i][j] = __builtin_amdgcn_mfma_f32_16x16x32_fp8_fp8(af[i], bfr[j], acc[i][j], 0, 0, 0);
        }
    }
    // epilogue: C/D layout col=lane&15, row=quad*4+reg (dtype-independent)
    #pragma unroll
    for (int i = 0; i < 4; ++i) {
        int rowb = row0 + wm * 64 + i * 16 + quad * 4;
        #pragma unroll
        for (int r = 0; r < 4; ++r) {
            int grow = rowb + r;
            #pragma unroll
            for (int j = 0; j < 4; ++j) {
                int gcol = col0 + wn * 64 + j * 16 + l16;
                float v = acc[i][j][r];
                if (RELU) v = fmaxf(v, 0.f);
                C[(size_t)grow * H_F + gcol] = f32_fp8(v);
            }
        }
    }
}

// ------------------------------------------------------------------
// GCN aggregation, 128-ch fp8 (layer-0, pre-GEMM), NO relu.
// ------------------------------------------------------------------
__global__ __launch_bounds__(256) void aggregate128(const u8* __restrict__ hw,
                                                    const float* __restrict__ dinv,
                                                    const int* __restrict__ offsets,
                                                    const unsigned int* __restrict__ csr_ew,
                                                    u8* __restrict__ hout) {
    int w = threadIdx.x >> 6;
    int lane = threadIdx.x & 63;
    int i = blockIdx.x * 4 + w;
    if (i >= N_NODES) return;
    float di = dinv[i];
    const u8* base = hw + (size_t)lane * 2;
    unsigned int su = *(const unsigned short*)(base + (size_t)i * IN_F);
    f32x2 sv = fp8x2_f32_lo(su);
    float s = di * di;
    float a0 = s * sv.x, a1 = s * sv.y;
    int t = offsets[i], end = offsets[i + 1];
    for (; t + 8 <= end; t += 8) {
        unsigned int e[8];
        unsigned int v[8];
        #pragma unroll
        for (int u = 0; u < 8; ++u) e[u] = csr_ew[t + u];
        #pragma unroll
        for (int u = 0; u < 8; ++u)
            v[u] = *(const unsigned short*)(base + (size_t)(e[u] & 0xffff) * IN_F);
        #pragma unroll
        for (int u = 0; u < 8; ++u) {
            float wq = bf2f((ushort)(e[u] >> 16));
            f32x2 f = fp8x2_f32_lo(v[u]);
            a0 += wq * f.x; a1 += wq * f.y;
        }
    }
    for (; t < end; ++t) {
        unsigned int e0 = csr_ew[t];
        unsigned int v0 = *(const unsigned short*)(base + (size_t)(e0 & 0xffff) * IN_F);
        float wq = bf2f((ushort)(e0 >> 16));
        f32x2 f = fp8x2_f32_lo(v0);
        a0 += wq * f.x; a1 += wq * f.y;
    }
    unsigned int o = f32_fp8x2_lo(a0, a1, 0u);
    *(unsigned short*)(hout + (size_t)i * IN_F + lane * 2) = (unsigned short)(o & 0xffff);
}

// ------------------------------------------------------------------
// GCN aggregation, 256-ch fp8, + relu. wave per node, lane = 4 channels.
// ------------------------------------------------------------------
__global__ __launch_bounds__(256) void aggregate256(const u8* __restrict__ hw,
                                                    const float* __restrict__ dinv,
                                                    const int* __restrict__ offsets,
                                                    const unsigned int* __restrict__ csr_ew,
                                                    u8* __restrict__ hout) {
    int w = threadIdx.x >> 6;
    int lane = threadIdx.x & 63;
    int i = blockIdx.x * 4 + w;
    if (i >= N_NODES) return;
    float di = dinv[i];
    const u8* base = hw + (size_t)lane * 4;
    unsigned int su = *(const unsigned int*)(base + (size_t)i * H_F);
    f32x2 slo = fp8x2_f32_lo(su), shi = fp8x2_f32_hi(su);
    float s = di * di;
    float a0 = s * slo.x, a1 = s * slo.y, a2 = s * shi.x, a3 = s * shi.y;
    int t = offsets[i], end = offsets[i + 1];
    for (; t + 8 <= end; t += 8) {
        unsigned int e[8];
        unsigned int v[8];
        #pragma unroll
        for (int u = 0; u < 8; ++u) e[u] = csr_ew[t + u];
        #pragma unroll
        for (int u = 0; u < 8; ++u)
            v[u] = *(const unsigned int*)(base + (size_t)(e[u] & 0xffff) * H_F);
        #pragma unroll
        for (int u = 0; u < 8; ++u) {
            float wq = bf2f((ushort)(e[u] >> 16));
            f32x2 lo = fp8x2_f32_lo(v[u]), hi = fp8x2_f32_hi(v[u]);
            a0 += wq * lo.x; a1 += wq * lo.y;
            a2 += wq * hi.x; a3 += wq * hi.y;
        }
    }
    for (; t < end; ++t) {
        unsigned int e0 = csr_ew[t];
        unsigned int v0 = *(const unsigned int*)(base + (size_t)(e0 & 0xffff) * H_F);
        float wq = bf2f((ushort)(e0 >> 16));
        f32x2 lo = fp8x2_f32_lo(v0), hi = fp8x2_f32_hi(v0);
        a0 += wq * lo.x; a1 += wq * lo.y;
        a2 += wq * hi.x; a3 += wq * hi.y;
    }
    unsigned int o = f32_fp8x2_lo(fmaxf(a0, 0.f), fmaxf(a1, 0.f), 0u);
    o = f32_fp8x2_hi(fmaxf(a2, 0.f), fmaxf(a3, 0.f), o);
    *(unsigned int*)(hout + (size_t)i * H_F + lane * 4) = o;
}

// ------------------------------------------------------------------
// Pool: (graph, node-chunk) blocks, fp32 atomic partial sums. fp8 input.
// ------------------------------------------------------------------
__global__ __launch_bounds__(256) void pool_part(const u8* __restrict__ h,
                                                 const int* __restrict__ gstart,
                                                 float* __restrict__ pooled) {
    int g = blockIdx.x;
    int s = gstart[g] + blockIdx.y * POOL_CHUNK;
    int e = min(gstart[g + 1], s + POOL_CHUNK);
    if (s >= e) return;
    int c = threadIdx.x;
    float sum = 0.f;
    for (int i = s; i < e; ++i) {
        f32x2 f = fp8x2_f32_lo((unsigned int)h[(size_t)i * H_F + c]);
        sum += f.x;
    }
    atomicAdd(&pooled[g * H_F + c], sum);
}

// ------------------------------------------------------------------
// Fused MLP head (all fp32)
// ------------------------------------------------------------------
__global__ __launch_bounds__(256) void mlp_head_kernel(const float* __restrict__ pooled,
                                                       const int* __restrict__ gstart,
                                                       const float* __restrict__ Wm1,
                                                       const float* __restrict__ bm1,
                                                       const float* __restrict__ Wm2,
                                                       const float* __restrict__ bm2,
                                                       float* __restrict__ out) {
    __shared__ float p[H_F];
    __shared__ float h[H_F];
    __shared__ float lastv[OUT_F];
    __shared__ float stats[2];
    int g = blockIdx.x, j = threadIdx.x;
    int cnt = gstart[g + 1] - gstart[g];
    p[j] = pooled[g * H_F + j] / (float)max(cnt, 1);
    __syncthreads();
    float acc = bm1[j];
    for (int k = 0; k < H_F; ++k) acc += p[k] * Wm1[k * H_F + j];
    h[j] = fmaxf(acc, 0.f);
    __syncthreads();
    if (j < OUT_F) {
        float a = bm2[j];
        for (int k = 0; k < H_F; ++k) a += h[k] * Wm2[k * OUT_F + j];
        lastv[j] = a;
    }
    __syncthreads();
    if (j == 0) {
        float m = -1e30f;
        for (int o = 0; o < OUT_F; ++o) m = fmaxf(m, lastv[o]);
        float s = 0.f;
        for (int o = 0; o < OUT_F; ++o) s += expf(lastv[o] - m);
        stats[0] = m; stats[1] = logf(s);
    }
    __syncthreads();
    if (j < OUT_F) {
        float v = lastv[j];
        out[g * OUT_F + j] = v - stats[0] - stats[1];
        out[(size_t)N_G * OUT_F + g * OUT_F + j] = 1.f / (1.f + expf(-v));
        out[(size_t)2 * N_G * OUT_F + g * OUT_F + j] = v;
    }
}

// ------------------------------------------------------------------
extern "C" void kernel_launch(void* const* d_in, const int* in_sizes, int n_in,
                              void* d_out, int out_size, void* d_ws, size_t ws_size,
                              hipStream_t stream) {
    const float* x   = (const float*)d_in[0];
    const int* edge_index = (const int*)d_in[1];
    const int* batch = (const int*)d_in[3];
    const float* W0  = (const float*)d_in[4];
    const float* W1  = (const float*)d_in[5];
    const float* W2  = (const float*)d_in[6];
    const float* Wm1 = (const float*)d_in[7];
    const float* bm1 = (const float*)d_in[8];
    const float* Wm2 = (const float*)d_in[9];
    const float* bm2 = (const float*)d_in[10];
    float* out = (float*)d_out;

    char* ws = (char*)d_ws;
    size_t off = 0;
    auto alloc = [&](size_t bytes) -> void* {
        void* p = ws + off; off += (bytes + 255) & ~(size_t)255; return p;
    };
    u8* xb       = (u8*)alloc((size_t)N_PAD * IN_F);
    u8* bufA     = (u8*)alloc((size_t)N_PAD * H_F);
    u8* bufB     = (u8*)alloc((size_t)N_PAD * H_F);
    u8* t0       = (u8*)alloc((size_t)N_PAD * IN_F);
    u8* W0t      = (u8*)alloc((size_t)H_F * IN_F);
    u8* W1t      = (u8*)alloc((size_t)H_F * H_F);
    u8* W2t      = (u8*)alloc((size_t)H_F * H_F);
    float* dinv    = (float*)alloc((size_t)N_NODES * 4);
    int*   counts  = (int*)alloc((size_t)N_NODES * 4);
    int*   offsets = (int*)alloc((size_t)(N_NODES + 1) * 4);
    int*   rank    = (int*)alloc((size_t)N_EDGES * 4);
    unsigned int* csr_ew = (unsigned int*)alloc((size_t)N_EDGES * 4);
    int*   csum    = (int*)alloc((size_t)256 * 4);
    int*   gstart  = (int*)alloc((size_t)(N_G + 1) * 4);
    float* pooled  = (float*)alloc((size_t)N_G * H_F * 4);

    const int* row = edge_index;
    const int* col = edge_index + N_EDGES;

    hipMemsetAsync(counts, 0, (size_t)N_NODES * 4, stream);
    hipMemsetAsync(pooled, 0, (size_t)N_G * H_F * 4, stream);

    prep_kernel<<<PREP_GS, 256, 0, stream>>>(col, counts, rank, x, xb,
                                             W0, W0t, W1, W1t, W2, W2t,
                                             batch, gstart);
    chunk_reduce<<<NCHUNKS, 256, 0, stream>>>(counts, csum, N_NODES);
    scan_dinv_kernel<<<NCHUNKS, 256, 0, stream>>>(counts, csum, offsets, dinv, N_NODES);
    fill_csr_kernel<<<3125, 256, 0, stream>>>(row, col, offsets, rank, dinv, csr_ew);

    dim3 gg(N_PAD / 128, H_F / 128);
    int agg_blocks = (N_NODES + 3) / 4;
    // layer 0: aggregate-first (linear ops commute), relu in GEMM epilogue
    aggregate128<<<agg_blocks, 256, 0, stream>>>(xb, dinv, offsets, csr_ew, t0);
    gemm_fp8<IN_F, true><<<gg, 256, 0, stream>>>(t0, W0t, bufA);
    // layer 1
    gemm_fp8<H_F, false><<<gg, 256, 0, stream>>>(bufA, W1t, bufB);
    aggregate256<<<agg_blocks, 256, 0, stream>>>(bufB, dinv, offsets, csr_ew, bufA);
    // layer 2
    gemm_fp8<H_F, false><<<gg, 256, 0, stream>>>(bufA, W2t, bufB);
    aggregate256<<<agg_blocks, 256, 0, stream>>>(bufB, dinv, offsets, csr_ew, bufA);

    dim3 pg(N_G, POOL_MAXCHUNKS);
    pool_part<<<pg, 256, 0, stream>>>(bufA, gstart, pooled);
    mlp_head_kernel<<<N_G, 256, 0, stream>>>(pooled, gstart, Wm1, bm1, Wm2, bm2, out);
}

// Round 12
// 330.851 us; speedup vs baseline: 1.1574x; 1.0632x over previous
//
#include <hip/hip_runtime.h>
#include <math.h>

#define N_NODES 50000
#define N_PAD   50048          // padded to multiple of 128 for GEMM tiles
#define N_EDGES 800000
#define CSR_CAP 1200000        // >= sum pad8(deg) <= 800000 + 50000*7
#define IN_F 128
#define H_F 256
#define OUT_F 10
#define N_G 128
#define POOL_CHUNK 128
#define POOL_MAXCHUNKS 16
#define NCHUNKS 196            // ceil(N_NODES/256)

typedef __attribute__((ext_vector_type(4))) float f32x4;
typedef __attribute__((ext_vector_type(2))) float f32x2;
typedef unsigned char u8;

// ---- fp8 e4m3 (OCP) helpers: HW packed converts (imm word-select) ----
__device__ inline f32x2 fp8x2_f32_lo(unsigned int v) {
    return __builtin_amdgcn_cvt_pk_f32_fp8(v, false);
}
__device__ inline f32x2 fp8x2_f32_hi(unsigned int v) {
    return __builtin_amdgcn_cvt_pk_f32_fp8(v, true);
}
__device__ inline unsigned int f32_fp8x2_lo(float a, float b, unsigned int old) {
    return __builtin_amdgcn_cvt_pk_fp8_f32(a, b, old, false);
}
__device__ inline unsigned int f32_fp8x2_hi(float a, float b, unsigned int old) {
    return __builtin_amdgcn_cvt_pk_fp8_f32(a, b, old, true);
}
__device__ inline u8 f32_fp8(float a) {
    return (u8)(f32_fp8x2_lo(a, a, 0u) & 0xff);
}
// ---- bf16 helpers (packed CSR weight) ----
__device__ inline ushort f2bf(float x) {
    union { float f; unsigned int u; } v; v.f = x;
    unsigned int r = v.u + 0x7fff + ((v.u >> 16) & 1);
    return (ushort)(r >> 16);
}
__device__ inline float bf2f(ushort u) {
    union { unsigned int u; float f; } v; v.u = ((unsigned int)u) << 16; return v.f;
}

// async global->LDS, 16 B per lane; lds dest = wave-uniform base + lane*16
__device__ inline void gl2lds16(const void* g, void* l) {
    __builtin_amdgcn_global_load_lds(
        (const __attribute__((address_space(1))) unsigned int*)g,
        (__attribute__((address_space(3))) unsigned int*)l,
        16, 0, 0);
}

// ------------------------------------------------------------------
// Mega-fused prep (block roles by blockIdx range)
// histogram role: 4 edges/thread (strided 256 in a 1024-edge chunk) ->
// 4 outstanding atomic chains/thread while 782 blocks keep TLP high.
// ------------------------------------------------------------------
#define PREP_CE   782                    // ceil(800000 / 1024)
#define PREP_CV   (PREP_CE + 6250)
#define PREP_T0   (PREP_CV + 128)
#define PREP_T1   (PREP_T0 + 256)
#define PREP_T2   (PREP_T1 + 256)
#define PREP_GS   (PREP_T2 + NCHUNKS)

__global__ __launch_bounds__(256) void prep_kernel(
    const int* __restrict__ col, int* __restrict__ counts, int* __restrict__ rank,
    const float* __restrict__ x, u8* __restrict__ xb,
    const float* __restrict__ W0, u8* __restrict__ W0t,
    const float* __restrict__ W1, u8* __restrict__ W1t,
    const float* __restrict__ W2, u8* __restrict__ W2t,
    const int* __restrict__ batch, int* __restrict__ gstart) {
    int b = blockIdx.x;
    int tid = threadIdx.x;
    if (b < PREP_CE) {
        int base = b * 1024 + tid;
        int c[4];
        #pragma unroll
        for (int u = 0; u < 4; ++u) {
            int e = base + u * 256;
            c[u] = (e < N_EDGES) ? col[e] : -1;
        }
        int rk[4];
        #pragma unroll
        for (int u = 0; u < 4; ++u)
            if (c[u] >= 0) rk[u] = atomicAdd(&counts[c[u]], 1);
        #pragma unroll
        for (int u = 0; u < 4; ++u)
            if (c[u] >= 0) rank[base + u * 256] = rk[u];
    } else if (b < PREP_CV) {
        int i = (b - PREP_CE) * 256 + tid;      // < 1,600,000 exactly
        float4 v = *(const float4*)(x + (size_t)i * 4);
        unsigned int p = f32_fp8x2_lo(v.x, v.y, 0u);
        p = f32_fp8x2_hi(v.z, v.w, p);
        *(unsigned int*)(xb + (size_t)i * 4) = p;
    } else if (b < PREP_T0) {
        int idx = (b - PREP_CV) * 256 + tid;    // < 32768
        int k = idx >> 8, nn = idx & 255;       // K=128, Nc=256
        W0t[nn * IN_F + k] = f32_fp8(W0[idx]);
    } else if (b < PREP_T1) {
        int idx = (b - PREP_T0) * 256 + tid;    // < 65536
        int k = idx >> 8, nn = idx & 255;
        W1t[nn * H_F + k] = f32_fp8(W1[idx]);
    } else if (b < PREP_T2) {
        int idx = (b - PREP_T1) * 256 + tid;
        int k = idx >> 8, nn = idx & 255;
        W2t[nn * H_F + k] = f32_fp8(W2[idx]);
    } else {
        int i = (b - PREP_T2) * 256 + tid;
        if (i >= N_NODES) return;
        int bb = batch[i];
        if (i == 0) {
            for (int g = 0; g <= bb; ++g) gstart[g] = 0;
        } else {
            int p = batch[i - 1];
            if (p != bb) { for (int g = p + 1; g <= bb; ++g) gstart[g] = i; }
        }
        if (i == N_NODES - 1) {
            for (int g = bb + 1; g <= N_G; ++g) gstart[g] = N_NODES;
        }
    }
}

// ------------------------------------------------------------------
// per-chunk sums of PADDED counts (196 blocks): pad8 per node so every
// edge list is a multiple of 8 (tail-free aggregate loops).
// ------------------------------------------------------------------
__global__ __launch_bounds__(256) void chunk_reduce(const int* __restrict__ counts,
                                                    int* __restrict__ csum, int n) {
    int i = blockIdx.x * 256 + threadIdx.x;
    int v = (i < n) ? ((counts[i] + 7) & ~7) : 0;
    #pragma unroll
    for (int off = 32; off; off >>= 1) v += __shfl_down(v, off);
    __shared__ int ws[4];
    if ((threadIdx.x & 63) == 0) ws[threadIdx.x >> 6] = v;
    __syncthreads();
    if (threadIdx.x == 0) csum[blockIdx.x] = ws[0] + ws[1] + ws[2] + ws[3];
}

// ------------------------------------------------------------------
// scan (over padded counts) + dinv (real counts), fully parallel
// ------------------------------------------------------------------
__global__ __launch_bounds__(256) void scan_dinv_kernel(const int* __restrict__ counts,
                                                        const int* __restrict__ csum,
                                                        int* __restrict__ offsets,
                                                        float* __restrict__ dinv, int n) {
    int tid = threadIdx.x;
    int lane = tid & 63, wid = tid >> 6;
    int cv = (tid < NCHUNKS) ? csum[tid] : 0;
    int xc = cv;
    #pragma unroll
    for (int off = 1; off < 64; off <<= 1) {
        int t = __shfl_up(xc, off);
        if (lane >= off) xc += t;
    }
    __shared__ int cw[4], cpre[4];
    __shared__ int cexcl[257];
    if (lane == 63) cw[wid] = xc;
    __syncthreads();
    if (tid == 0) { int s = 0; for (int k = 0; k < 4; ++k) { cpre[k] = s; s += cw[k]; } }
    __syncthreads();
    cexcl[tid] = cpre[wid] + xc - cv;
    if (tid == 255) cexcl[256] = cpre[3] + cw[3];
    __syncthreads();
    int base = cexcl[blockIdx.x];
    int i = blockIdx.x * 256 + tid;
    int v = (i < n) ? counts[i] : 0;
    int pv = (v + 7) & ~7;
    int x = pv;
    #pragma unroll
    for (int off = 1; off < 64; off <<= 1) {
        int t = __shfl_up(x, off);
        if (lane >= off) x += t;
    }
    __shared__ int wsum[4], wpre[4];
    if (lane == 63) wsum[wid] = x;
    __syncthreads();
    if (tid == 0) { int s = 0; for (int k = 0; k < 4; ++k) { wpre[k] = s; s += wsum[k]; } }
    __syncthreads();
    if (i < n) {
        offsets[i] = base + wpre[wid] + x - pv;   // exclusive, padded
        dinv[i] = rsqrtf((float)(v + 1));
    }
    if (blockIdx.x == 0 && tid == 0) offsets[n] = cexcl[NCHUNKS];
}

// Packed CSR: entry = src (16 bits) | bf16 weight << 16; slot = offsets[c]
// + rank[e] (atomic-free). Padding slots stay 0 (w=0 -> contributes 0).
__global__ __launch_bounds__(256) void fill_csr_kernel(const int* __restrict__ row,
                                                       const int* __restrict__ col,
                                                       const int* __restrict__ offsets,
                                                       const int* __restrict__ rank,
                                                       const float* __restrict__ dinv,
                                                       unsigned int* __restrict__ csr_ew) {
    int e = blockIdx.x * 256 + threadIdx.x;
    if (e < N_EDGES) {
        int c = col[e];
        int r = row[e];
        int k = rank[e];
        float w = dinv[c] * dinv[r];
        csr_ew[offsets[c] + k] = (unsigned int)r | ((unsigned int)f2bf(w) << 16);
    }
}

// ------------------------------------------------------------------
// fp8 MFMA GEMM: C[N_PAD x 256] = A[N_PAD x K] @ Bt^T   (Bt is [256][K], fp8)
// 128x128 tile / block (4 waves 2x2), BK=128, async global_load_lds staging.
// ------------------------------------------------------------------
template <int K, bool RELU>
__global__ __launch_bounds__(256) void gemm_fp8(const u8* __restrict__ A,
                                                const u8* __restrict__ Bt,
                                                u8* __restrict__ C) {
    __shared__ u8 As[4 * 4096];
    __shared__ u8 Bs[4 * 4096];
    int tid = threadIdx.x;
    int lane = tid & 63;
    int w = tid >> 6;
    int wm = w & 1, wn = w >> 1;
    int l16 = lane & 15, quad = lane >> 4;
    int row0 = blockIdx.x * 128;
    int col0 = blockIdx.y * 128;
    f32x4 acc[4][4] = {};

    int sr = tid >> 1;             // staging row 0..127
    int sh = (tid & 1) * 16;       // half-plane-row byte offset
    const u8* ga = A + (size_t)(row0 + sr) * K + sh;
    const u8* gb = Bt + (size_t)(col0 + sr) * K + sh;

    #pragma unroll
    for (int k0 = 0; k0 < K; k0 += 128) {
        if (k0) __syncthreads();
        #pragma unroll
        for (int q = 0; q < 4; ++q) {   // k-plane within stage
            gl2lds16(ga + k0 + q * 32, As + q * 4096 + w * 1024);
            gl2lds16(gb + k0 + q * 32, Bs + q * 4096 + w * 1024);
        }
        __syncthreads();
        #pragma unroll
        for (int h = 0; h < 4; ++h) {
            long af[4], bfr[4];
            #pragma unroll
            for (int i = 0; i < 4; ++i)
                af[i] = *(const long*)&As[h * 4096 + (wm * 64 + i * 16 + l16) * 32 + quad * 8];
            #pragma unroll
            for (int j = 0; j < 4; ++j)
                bfr[j] = *(const long*)&Bs[h * 4096 + (wn * 64 + j * 16 + l16) * 32 + quad * 8];
            #pragma unroll
            for (int i = 0; i < 4; ++i)
                #pragma unroll
                for (int j = 0; j < 4; ++j)
                    acc[i][j] = __builtin_amdgcn_mfma_f32_16x16x32_fp8_fp8(af[i], bfr[j], acc[i][j], 0, 0, 0);
        }
    }
    // epilogue: C/D layout col=lane&15, row=quad*4+reg (dtype-independent)
    #pragma unroll
    for (int i = 0; i < 4; ++i) {
        int rowb = row0 + wm * 64 + i * 16 + quad * 4;
        #pragma unroll
        for (int r = 0; r < 4; ++r) {
            int grow = rowb + r;
            #pragma unroll
            for (int j = 0; j < 4; ++j) {
                int gcol = col0 + wn * 64 + j * 16 + l16;
                float v = acc[i][j][r];
                if (RELU) v = fmaxf(v, 0.f);
                C[(size_t)grow * H_F + gcol] = f32_fp8(v);
            }
        }
    }
}

// ------------------------------------------------------------------
// GCN aggregation, 128-ch fp8 (layer-0, pre-GEMM), NO relu.
// Edge lists padded to x8 -> tail-free; csr loads as 2 aligned uint4.
// ------------------------------------------------------------------
__global__ __launch_bounds__(256) void aggregate128(const u8* __restrict__ hw,
                                                    const float* __restrict__ dinv,
                                                    const int* __restrict__ offsets,
                                                    const unsigned int* __restrict__ csr_ew,
                                                    u8* __restrict__ hout) {
    int w = threadIdx.x >> 6;
    int lane = threadIdx.x & 63;
    int i = blockIdx.x * 4 + w;
    if (i >= N_NODES) return;
    float di = dinv[i];
    const u8* base = hw + (size_t)lane * 2;
    unsigned int su = *(const unsigned short*)(base + (size_t)i * IN_F);
    f32x2 sv = fp8x2_f32_lo(su);
    float s = di * di;
    float a0 = s * sv.x, a1 = s * sv.y;
    int t = offsets[i], end = offsets[i + 1];
    for (; t < end; t += 8) {
        uint4 eA = *(const uint4*)(csr_ew + t);
        uint4 eB = *(const uint4*)(csr_ew + t + 4);
        unsigned int e[8] = {eA.x, eA.y, eA.z, eA.w, eB.x, eB.y, eB.z, eB.w};
        unsigned int v[8];
        #pragma unroll
        for (int u = 0; u < 8; ++u)
            v[u] = *(const unsigned short*)(base + (size_t)(e[u] & 0xffff) * IN_F);
        #pragma unroll
        for (int u = 0; u < 8; ++u) {
            float wq = bf2f((ushort)(e[u] >> 16));
            f32x2 f = fp8x2_f32_lo(v[u]);
            a0 += wq * f.x; a1 += wq * f.y;
        }
    }
    unsigned int o = f32_fp8x2_lo(a0, a1, 0u);
    *(unsigned short*)(hout + (size_t)i * IN_F + lane * 2) = (unsigned short)(o & 0xffff);
}

// ------------------------------------------------------------------
// GCN aggregation, 256-ch fp8, + relu. Tail-free (padded edge lists).
// ------------------------------------------------------------------
__global__ __launch_bounds__(256) void aggregate256(const u8* __restrict__ hw,
                                                    const float* __restrict__ dinv,
                                                    const int* __restrict__ offsets,
                                                    const unsigned int* __restrict__ csr_ew,
                                                    u8* __restrict__ hout) {
    int w = threadIdx.x >> 6;
    int lane = threadIdx.x & 63;
    int i = blockIdx.x * 4 + w;
    if (i >= N_NODES) return;
    float di = dinv[i];
    const u8* base = hw + (size_t)lane * 4;
    unsigned int su = *(const unsigned int*)(base + (size_t)i * H_F);
    f32x2 slo = fp8x2_f32_lo(su), shi = fp8x2_f32_hi(su);
    float s = di * di;
    float a0 = s * slo.x, a1 = s * slo.y, a2 = s * shi.x, a3 = s * shi.y;
    int t = offsets[i], end = offsets[i + 1];
    for (; t < end; t += 8) {
        uint4 eA = *(const uint4*)(csr_ew + t);
        uint4 eB = *(const uint4*)(csr_ew + t + 4);
        unsigned int e[8] = {eA.x, eA.y, eA.z, eA.w, eB.x, eB.y, eB.z, eB.w};
        unsigned int v[8];
        #pragma unroll
        for (int u = 0; u < 8; ++u)
            v[u] = *(const unsigned int*)(base + (size_t)(e[u] & 0xffff) * H_F);
        #pragma unroll
        for (int u = 0; u < 8; ++u) {
            float wq = bf2f((ushort)(e[u] >> 16));
            f32x2 lo = fp8x2_f32_lo(v[u]), hi = fp8x2_f32_hi(v[u]);
            a0 += wq * lo.x; a1 += wq * lo.y;
            a2 += wq * hi.x; a3 += wq * hi.y;
        }
    }
    unsigned int o = f32_fp8x2_lo(fmaxf(a0, 0.f), fmaxf(a1, 0.f), 0u);
    o = f32_fp8x2_hi(fmaxf(a2, 0.f), fmaxf(a3, 0.f), o);
    *(unsigned int*)(hout + (size_t)i * H_F + lane * 4) = o;
}

// ------------------------------------------------------------------
// Pool: (graph, node-chunk) blocks, fp32 atomic partial sums. fp8 input.
// ------------------------------------------------------------------
__global__ __launch_bounds__(256) void pool_part(const u8* __restrict__ h,
                                                 const int* __restrict__ gstart,
                                                 float* __restrict__ pooled) {
    int g = blockIdx.x;
    int s = gstart[g] + blockIdx.y * POOL_CHUNK;
    int e = min(gstart[g + 1], s + POOL_CHUNK);
    if (s >= e) return;
    int c = threadIdx.x;
    float sum = 0.f;
    for (int i = s; i < e; ++i) {
        f32x2 f = fp8x2_f32_lo((unsigned int)h[(size_t)i * H_F + c]);
        sum += f.x;
    }
    atomicAdd(&pooled[g * H_F + c], sum);
}

// ------------------------------------------------------------------
// Fused MLP head (all fp32)
// ------------------------------------------------------------------
__global__ __launch_bounds__(256) void mlp_head_kernel(const float* __restrict__ pooled,
                                                       const int* __restrict__ gstart,
                                                       const float* __restrict__ Wm1,
                                                       const float* __restrict__ bm1,
                                                       const float* __restrict__ Wm2,
                                                       const float* __restrict__ bm2,
                                                       float* __restrict__ out) {
    __shared__ float p[H_F];
    __shared__ float h[H_F];
    __shared__ float lastv[OUT_F];
    __shared__ float stats[2];
    int g = blockIdx.x, j = threadIdx.x;
    int cnt = gstart[g + 1] - gstart[g];
    p[j] = pooled[g * H_F + j] / (float)max(cnt, 1);
    __syncthreads();
    float acc = bm1[j];
    for (int k = 0; k < H_F; ++k) acc += p[k] * Wm1[k * H_F + j];
    h[j] = fmaxf(acc, 0.f);
    __syncthreads();
    if (j < OUT_F) {
        float a = bm2[j];
        for (int k = 0; k < H_F; ++k) a += h[k] * Wm2[k * OUT_F + j];
        lastv[j] = a;
    }
    __syncthreads();
    if (j == 0) {
        float m = -1e30f;
        for (int o = 0; o < OUT_F; ++o) m = fmaxf(m, lastv[o]);
        float s = 0.f;
        for (int o = 0; o < OUT_F; ++o) s += expf(lastv[o] - m);
        stats[0] = m; stats[1] = logf(s);
    }
    __syncthreads();
    if (j < OUT_F) {
        float v = lastv[j];
        out[g * OUT_F + j] = v - stats[0] - stats[1];
        out[(size_t)N_G * OUT_F + g * OUT_F + j] = 1.f / (1.f + expf(-v));
        out[(size_t)2 * N_G * OUT_F + g * OUT_F + j] = v;
    }
}

// ------------------------------------------------------------------
extern "C" void kernel_launch(void* const* d_in, const int* in_sizes, int n_in,
                              void* d_out, int out_size, void* d_ws, size_t ws_size,
                              hipStream_t stream) {
    const float* x   = (const float*)d_in[0];
    const int* edge_index = (const int*)d_in[1];
    const int* batch = (const int*)d_in[3];
    const float* W0  = (const float*)d_in[4];
    const float* W1  = (const float*)d_in[5];
    const float* W2  = (const float*)d_in[6];
    const float* Wm1 = (const float*)d_in[7];
    const float* bm1 = (const float*)d_in[8];
    const float* Wm2 = (const float*)d_in[9];
    const float* bm2 = (const float*)d_in[10];
    float* out = (float*)d_out;

    char* ws = (char*)d_ws;
    size_t off = 0;
    auto alloc = [&](size_t bytes) -> void* {
        void* p = ws + off; off += (bytes + 255) & ~(size_t)255; return p;
    };
    u8* xb       = (u8*)alloc((size_t)N_PAD * IN_F);
    u8* bufA     = (u8*)alloc((size_t)N_PAD * H_F);
    u8* bufB     = (u8*)alloc((size_t)N_PAD * H_F);
    u8* t0       = (u8*)alloc((size_t)N_PAD * IN_F);
    u8* W0t      = (u8*)alloc((size_t)H_F * IN_F);
    u8* W1t      = (u8*)alloc((size_t)H_F * H_F);
    u8* W2t      = (u8*)alloc((size_t)H_F * H_F);
    float* dinv    = (float*)alloc((size_t)N_NODES * 4);
    int*   counts  = (int*)alloc((size_t)N_NODES * 4);
    int*   offsets = (int*)alloc((size_t)(N_NODES + 1) * 4);
    int*   rank    = (int*)alloc((size_t)N_EDGES * 4);
    unsigned int* csr_ew = (unsigned int*)alloc((size_t)CSR_CAP * 4);
    int*   csum    = (int*)alloc((size_t)256 * 4);
    int*   gstart  = (int*)alloc((size_t)(N_G + 1) * 4);
    float* pooled  = (float*)alloc((size_t)N_G * H_F * 4);

    const int* row = edge_index;
    const int* col = edge_index + N_EDGES;

    hipMemsetAsync(counts, 0, (size_t)N_NODES * 4, stream);
    hipMemsetAsync(pooled, 0, (size_t)N_G * H_F * 4, stream);
    hipMemsetAsync(csr_ew, 0, (size_t)CSR_CAP * 4, stream);   // padding entries = w0

    prep_kernel<<<PREP_GS, 256, 0, stream>>>(col, counts, rank, x, xb,
                                             W0, W0t, W1, W1t, W2, W2t,
                                             batch, gstart);
    chunk_reduce<<<NCHUNKS, 256, 0, stream>>>(counts, csum, N_NODES);
    scan_dinv_kernel<<<NCHUNKS, 256, 0, stream>>>(counts, csum, offsets, dinv, N_NODES);
    fill_csr_kernel<<<3125, 256, 0, stream>>>(row, col, offsets, rank, dinv, csr_ew);

    dim3 gg(N_PAD / 128, H_F / 128);
    int agg_blocks = (N_NODES + 3) / 4;
    // layer 0: aggregate-first (linear ops commute), relu in GEMM epilogue
    aggregate128<<<agg_blocks, 256, 0, stream>>>(xb, dinv, offsets, csr_ew, t0);
    gemm_fp8<IN_F, true><<<gg, 256, 0, stream>>>(t0, W0t, bufA);
    // layer 1
    gemm_fp8<H_F, false><<<gg, 256, 0, stream>>>(bufA, W1t, bufB);
    aggregate256<<<agg_blocks, 256, 0, stream>>>(bufB, dinv, offsets, csr_ew, bufA);
    // layer 2
    gemm_fp8<H_F, false><<<gg, 256, 0, stream>>>(bufA, W2t, bufB);
    aggregate256<<<agg_blocks, 256, 0, stream>>>(bufB, dinv, offsets, csr_ew, bufA);

    dim3 pg(N_G, POOL_MAXCHUNKS);
    pool_part<<<pg, 256, 0, stream>>>(bufA, gstart, pooled);
    mlp_head_kernel<<<N_G, 256, 0, stream>>>(pooled, gstart, Wm1, bm1, Wm2, bm2, out);
}

// Round 13
// 328.062 us; speedup vs baseline: 1.1673x; 1.0085x over previous
//
#include <hip/hip_runtime.h>
#include <math.h>

#define N_NODES 50000
#define N_PAD   50048          // padded to multiple of 128 for GEMM tiles
#define N_EDGES 800000
#define CSR_CAP 1200000        // >= sum pad8(deg) <= 800000 + 50000*7
#define IN_F 128
#define H_F 256
#define OUT_F 10
#define N_G 128
#define POOL_CHUNK 128
#define POOL_MAXCHUNKS 16
#define NCHUNKS 196            // ceil(N_NODES/256)

typedef __attribute__((ext_vector_type(4))) float f32x4;
typedef __attribute__((ext_vector_type(2))) float f32x2;
typedef unsigned char u8;

// ---- fp8 e4m3 (OCP) helpers: HW packed converts (imm word-select) ----
__device__ inline f32x2 fp8x2_f32_lo(unsigned int v) {
    return __builtin_amdgcn_cvt_pk_f32_fp8(v, false);
}
__device__ inline f32x2 fp8x2_f32_hi(unsigned int v) {
    return __builtin_amdgcn_cvt_pk_f32_fp8(v, true);
}
__device__ inline unsigned int f32_fp8x2_lo(float a, float b, unsigned int old) {
    return __builtin_amdgcn_cvt_pk_fp8_f32(a, b, old, false);
}
__device__ inline unsigned int f32_fp8x2_hi(float a, float b, unsigned int old) {
    return __builtin_amdgcn_cvt_pk_fp8_f32(a, b, old, true);
}
__device__ inline u8 f32_fp8(float a) {
    return (u8)(f32_fp8x2_lo(a, a, 0u) & 0xff);
}
// ---- bf16 helpers (packed CSR weight) ----
__device__ inline ushort f2bf(float x) {
    union { float f; unsigned int u; } v; v.f = x;
    unsigned int r = v.u + 0x7fff + ((v.u >> 16) & 1);
    return (ushort)(r >> 16);
}
__device__ inline float bf2f(ushort u) {
    union { unsigned int u; float f; } v; v.u = ((unsigned int)u) << 16; return v.f;
}

// async global->LDS, 16 B per lane; lds dest = wave-uniform base + lane*16
__device__ inline void gl2lds16(const void* g, void* l) {
    __builtin_amdgcn_global_load_lds(
        (const __attribute__((address_space(1))) unsigned int*)g,
        (__attribute__((address_space(3))) unsigned int*)l,
        16, 0, 0);
}

// ------------------------------------------------------------------
// Histogram of edge destinations + per-edge rank (atomic return value).
// 4 edges/thread, 782 blocks. SPLIT from prep for counter attribution.
// ------------------------------------------------------------------
__global__ __launch_bounds__(256) void histo_kernel(const int* __restrict__ col,
                                                    int* __restrict__ counts,
                                                    int* __restrict__ rank) {
    int base = blockIdx.x * 1024 + threadIdx.x;
    int c[4];
    #pragma unroll
    for (int u = 0; u < 4; ++u) {
        int e = base + u * 256;
        c[u] = (e < N_EDGES) ? col[e] : -1;
    }
    int rk[4];
    #pragma unroll
    for (int u = 0; u < 4; ++u)
        if (c[u] >= 0) rk[u] = atomicAdd(&counts[c[u]], 1);
    #pragma unroll
    for (int u = 0; u < 4; ++u)
        if (c[u] >= 0) rank[base + u * 256] = rk[u];
}

// ------------------------------------------------------------------
// Converts + graph starts (block roles by blockIdx range)
// ------------------------------------------------------------------
#define CVT_X    6250
#define CVT_T0   (CVT_X + 128)
#define CVT_T1   (CVT_T0 + 256)
#define CVT_T2   (CVT_T1 + 256)
#define CVT_GS   (CVT_T2 + NCHUNKS)

__global__ __launch_bounds__(256) void convert_kernel(
    const float* __restrict__ x, u8* __restrict__ xb,
    const float* __restrict__ W0, u8* __restrict__ W0t,
    const float* __restrict__ W1, u8* __restrict__ W1t,
    const float* __restrict__ W2, u8* __restrict__ W2t,
    const int* __restrict__ batch, int* __restrict__ gstart) {
    int b = blockIdx.x;
    int tid = threadIdx.x;
    if (b < CVT_X) {
        int i = b * 256 + tid;                  // < 1,600,000 exactly
        float4 v = *(const float4*)(x + (size_t)i * 4);
        unsigned int p = f32_fp8x2_lo(v.x, v.y, 0u);
        p = f32_fp8x2_hi(v.z, v.w, p);
        *(unsigned int*)(xb + (size_t)i * 4) = p;
    } else if (b < CVT_T0) {
        int idx = (b - CVT_X) * 256 + tid;      // < 32768
        int k = idx >> 8, nn = idx & 255;       // K=128, Nc=256
        W0t[nn * IN_F + k] = f32_fp8(W0[idx]);
    } else if (b < CVT_T1) {
        int idx = (b - CVT_T0) * 256 + tid;     // < 65536
        int k = idx >> 8, nn = idx & 255;
        W1t[nn * H_F + k] = f32_fp8(W1[idx]);
    } else if (b < CVT_T2) {
        int idx = (b - CVT_T1) * 256 + tid;
        int k = idx >> 8, nn = idx & 255;
        W2t[nn * H_F + k] = f32_fp8(W2[idx]);
    } else {
        int i = (b - CVT_T2) * 256 + tid;
        if (i >= N_NODES) return;
        int bb = batch[i];
        if (i == 0) {
            for (int g = 0; g <= bb; ++g) gstart[g] = 0;
        } else {
            int p = batch[i - 1];
            if (p != bb) { for (int g = p + 1; g <= bb; ++g) gstart[g] = i; }
        }
        if (i == N_NODES - 1) {
            for (int g = bb + 1; g <= N_G; ++g) gstart[g] = N_NODES;
        }
    }
}

// ------------------------------------------------------------------
// per-chunk sums of PADDED counts (196 blocks) + zero `pooled`
// ------------------------------------------------------------------
__global__ __launch_bounds__(256) void chunk_reduce(const int* __restrict__ counts,
                                                    int* __restrict__ csum,
                                                    float* __restrict__ pooled, int n) {
    if (blockIdx.x < 128) pooled[blockIdx.x * 256 + threadIdx.x] = 0.f;
    int i = blockIdx.x * 256 + threadIdx.x;
    int v = (i < n) ? ((counts[i] + 7) & ~7) : 0;
    #pragma unroll
    for (int off = 32; off; off >>= 1) v += __shfl_down(v, off);
    __shared__ int ws[4];
    if ((threadIdx.x & 63) == 0) ws[threadIdx.x >> 6] = v;
    __syncthreads();
    if (threadIdx.x == 0) csum[blockIdx.x] = ws[0] + ws[1] + ws[2] + ws[3];
}

// ------------------------------------------------------------------
// scan (over padded counts) + dinv (real counts) + zero padding CSR slots
// ------------------------------------------------------------------
__global__ __launch_bounds__(256) void scan_dinv_kernel(const int* __restrict__ counts,
                                                        const int* __restrict__ csum,
                                                        int* __restrict__ offsets,
                                                        float* __restrict__ dinv,
                                                        unsigned int* __restrict__ csr_ew,
                                                        int n) {
    int tid = threadIdx.x;
    int lane = tid & 63, wid = tid >> 6;
    int cv = (tid < NCHUNKS) ? csum[tid] : 0;
    int xc = cv;
    #pragma unroll
    for (int off = 1; off < 64; off <<= 1) {
        int t = __shfl_up(xc, off);
        if (lane >= off) xc += t;
    }
    __shared__ int cw[4], cpre[4];
    __shared__ int cexcl[257];
    if (lane == 63) cw[wid] = xc;
    __syncthreads();
    if (tid == 0) { int s = 0; for (int k = 0; k < 4; ++k) { cpre[k] = s; s += cw[k]; } }
    __syncthreads();
    cexcl[tid] = cpre[wid] + xc - cv;
    if (tid == 255) cexcl[256] = cpre[3] + cw[3];
    __syncthreads();
    int base = cexcl[blockIdx.x];
    int i = blockIdx.x * 256 + tid;
    int v = (i < n) ? counts[i] : 0;
    int pv = (v + 7) & ~7;
    int x = pv;
    #pragma unroll
    for (int off = 1; off < 64; off <<= 1) {
        int t = __shfl_up(x, off);
        if (lane >= off) x += t;
    }
    __shared__ int wsum[4], wpre[4];
    if (lane == 63) wsum[wid] = x;
    __syncthreads();
    if (tid == 0) { int s = 0; for (int k = 0; k < 4; ++k) { wpre[k] = s; s += wsum[k]; } }
    __syncthreads();
    if (i < n) {
        int o = base + wpre[wid] + x - pv;       // exclusive, padded
        offsets[i] = o;
        dinv[i] = rsqrtf((float)(v + 1));
        for (int z = v; z < pv; ++z) csr_ew[o + z] = 0u;   // zero padding slots
    }
    if (blockIdx.x == 0 && tid == 0) offsets[n] = cexcl[NCHUNKS];
}

// Packed CSR: entry = src (16 bits) | bf16 weight << 16; slot = offsets[c]
// + rank[e] (atomic-free). 1 edge/thread, full TLP.
__global__ __launch_bounds__(256) void fill_csr_kernel(const int* __restrict__ row,
                                                       const int* __restrict__ col,
                                                       const int* __restrict__ offsets,
                                                       const int* __restrict__ rank,
                                                       const float* __restrict__ dinv,
                                                       unsigned int* __restrict__ csr_ew) {
    int e = blockIdx.x * 256 + threadIdx.x;
    if (e < N_EDGES) {
        int c = col[e];
        int r = row[e];
        int k = rank[e];
        float w = dinv[c] * dinv[r];
        csr_ew[offsets[c] + k] = (unsigned int)r | ((unsigned int)f2bf(w) << 16);
    }
}

// ------------------------------------------------------------------
// fp8 MFMA GEMM: C[N_PAD x 256] = A[N_PAD x K] @ Bt^T   (Bt is [256][K], fp8)
// 128x128 tile / block (4 waves 2x2), BK=128, async global_load_lds staging.
// ------------------------------------------------------------------
template <int K, bool RELU>
__global__ __launch_bounds__(256) void gemm_fp8(const u8* __restrict__ A,
                                                const u8* __restrict__ Bt,
                                                u8* __restrict__ C) {
    __shared__ u8 As[4 * 4096];
    __shared__ u8 Bs[4 * 4096];
    int tid = threadIdx.x;
    int lane = tid & 63;
    int w = tid >> 6;
    int wm = w & 1, wn = w >> 1;
    int l16 = lane & 15, quad = lane >> 4;
    int row0 = blockIdx.x * 128;
    int col0 = blockIdx.y * 128;
    f32x4 acc[4][4] = {};

    int sr = tid >> 1;             // staging row 0..127
    int sh = (tid & 1) * 16;       // half-plane-row byte offset
    const u8* ga = A + (size_t)(row0 + sr) * K + sh;
    const u8* gb = Bt + (size_t)(col0 + sr) * K + sh;

    #pragma unroll
    for (int k0 = 0; k0 < K; k0 += 128) {
        if (k0) __syncthreads();
        #pragma unroll
        for (int q = 0; q < 4; ++q) {   // k-plane within stage
            gl2lds16(ga + k0 + q * 32, As + q * 4096 + w * 1024);
            gl2lds16(gb + k0 + q * 32, Bs + q * 4096 + w * 1024);
        }
        __syncthreads();
        #pragma unroll
        for (int h = 0; h < 4; ++h) {
            long af[4], bfr[4];
            #pragma unroll
            for (int i = 0; i < 4; ++i)
                af[i] = *(const long*)&As[h * 4096 + (wm * 64 + i * 16 + l16) * 32 + quad * 8];
            #pragma unroll
            for (int j = 0; j < 4; ++j)
                bfr[j] = *(const long*)&Bs[h * 4096 + (wn * 64 + j * 16 + l16) * 32 + quad * 8];
            #pragma unroll
            for (int i = 0; i < 4; ++i)
                #pragma unroll
                for (int j = 0; j < 4; ++j)
                    acc[i][j] = __builtin_amdgcn_mfma_f32_16x16x32_fp8_fp8(af[i], bfr[j], acc[i][j], 0, 0, 0);
        }
    }
    // epilogue: C/D layout col=lane&15, row=quad*4+reg (dtype-independent)
    #pragma unroll
    for (int i = 0; i < 4; ++i) {
        int rowb = row0 + wm * 64 + i * 16 + quad * 4;
        #pragma unroll
        for (int r = 0; r < 4; ++r) {
            int grow = rowb + r;
            #pragma unroll
            for (int j = 0; j < 4; ++j) {
                int gcol = col0 + wn * 64 + j * 16 + l16;
                float v = acc[i][j][r];
                if (RELU) v = fmaxf(v, 0.f);
                C[(size_t)grow * H_F + gcol] = f32_fp8(v);
            }
        }
    }
}

// ------------------------------------------------------------------
// GCN aggregation, 128-ch fp8 (layer-0, pre-GEMM), NO relu.
// Padded x8 edge lists; next descriptor group prefetched (sw pipeline).
// ------------------------------------------------------------------
__global__ __launch_bounds__(256) void aggregate128(const u8* __restrict__ hw,
                                                    const float* __restrict__ dinv,
                                                    const int* __restrict__ offsets,
                                                    const unsigned int* __restrict__ csr_ew,
                                                    u8* __restrict__ hout) {
    int w = threadIdx.x >> 6;
    int lane = threadIdx.x & 63;
    int i = blockIdx.x * 4 + w;
    if (i >= N_NODES) return;
    float di = dinv[i];
    const u8* base = hw + (size_t)lane * 2;
    unsigned int su = *(const unsigned short*)(base + (size_t)i * IN_F);
    f32x2 sv = fp8x2_f32_lo(su);
    float s = di * di;
    float a0 = s * sv.x, a1 = s * sv.y;
    int t = offsets[i], end = offsets[i + 1];
    if (t < end) {
        uint4 eA = *(const uint4*)(csr_ew + t);
        uint4 eB = *(const uint4*)(csr_ew + t + 4);
        for (; t < end; t += 8) {
            uint4 nA, nB;
            if (t + 8 < end) {
                nA = *(const uint4*)(csr_ew + t + 8);
                nB = *(const uint4*)(csr_ew + t + 12);
            }
            unsigned int e[8] = {eA.x, eA.y, eA.z, eA.w, eB.x, eB.y, eB.z, eB.w};
            unsigned int v[8];
            #pragma unroll
            for (int u = 0; u < 8; ++u)
                v[u] = *(const unsigned short*)(base + (size_t)(e[u] & 0xffff) * IN_F);
            #pragma unroll
            for (int u = 0; u < 8; ++u) {
                float wq = bf2f((ushort)(e[u] >> 16));
                f32x2 f = fp8x2_f32_lo(v[u]);
                a0 += wq * f.x; a1 += wq * f.y;
            }
            eA = nA; eB = nB;
        }
    }
    unsigned int o = f32_fp8x2_lo(a0, a1, 0u);
    *(unsigned short*)(hout + (size_t)i * IN_F + lane * 2) = (unsigned short)(o & 0xffff);
}

// ------------------------------------------------------------------
// GCN aggregation, 256-ch fp8, + relu. Padded, pipelined.
// ------------------------------------------------------------------
__global__ __launch_bounds__(256) void aggregate256(const u8* __restrict__ hw,
                                                    const float* __restrict__ dinv,
                                                    const int* __restrict__ offsets,
                                                    const unsigned int* __restrict__ csr_ew,
                                                    u8* __restrict__ hout) {
    int w = threadIdx.x >> 6;
    int lane = threadIdx.x & 63;
    int i = blockIdx.x * 4 + w;
    if (i >= N_NODES) return;
    float di = dinv[i];
    const u8* base = hw + (size_t)lane * 4;
    unsigned int su = *(const unsigned int*)(base + (size_t)i * H_F);
    f32x2 slo = fp8x2_f32_lo(su), shi = fp8x2_f32_hi(su);
    float s = di * di;
    float a0 = s * slo.x, a1 = s * slo.y, a2 = s * shi.x, a3 = s * shi.y;
    int t = offsets[i], end = offsets[i + 1];
    if (t < end) {
        uint4 eA = *(const uint4*)(csr_ew + t);
        uint4 eB = *(const uint4*)(csr_ew + t + 4);
        for (; t < end; t += 8) {
            uint4 nA, nB;
            if (t + 8 < end) {
                nA = *(const uint4*)(csr_ew + t + 8);
                nB = *(const uint4*)(csr_ew + t + 12);
            }
            unsigned int e[8] = {eA.x, eA.y, eA.z, eA.w, eB.x, eB.y, eB.z, eB.w};
            unsigned int v[8];
            #pragma unroll
            for (int u = 0; u < 8; ++u)
                v[u] = *(const unsigned int*)(base + (size_t)(e[u] & 0xffff) * H_F);
            #pragma unroll
            for (int u = 0; u < 8; ++u) {
                float wq = bf2f((ushort)(e[u] >> 16));
                f32x2 lo = fp8x2_f32_lo(v[u]), hi = fp8x2_f32_hi(v[u]);
                a0 += wq * lo.x; a1 += wq * lo.y;
                a2 += wq * hi.x; a3 += wq * hi.y;
            }
            eA = nA; eB = nB;
        }
    }
    unsigned int o = f32_fp8x2_lo(fmaxf(a0, 0.f), fmaxf(a1, 0.f), 0u);
    o = f32_fp8x2_hi(fmaxf(a2, 0.f), fmaxf(a3, 0.f), o);
    *(unsigned int*)(hout + (size_t)i * H_F + lane * 4) = o;
}

// ------------------------------------------------------------------
// Pool: (graph, node-chunk) blocks, fp32 atomic partial sums. fp8 input.
// ------------------------------------------------------------------
__global__ __launch_bounds__(256) void pool_part(const u8* __restrict__ h,
                                                 const int* __restrict__ gstart,
                                                 float* __restrict__ pooled) {
    int g = blockIdx.x;
    int s = gstart[g] + blockIdx.y * POOL_CHUNK;
    int e = min(gstart[g + 1], s + POOL_CHUNK);
    if (s >= e) return;
    int c = threadIdx.x;
    float sum = 0.f;
    for (int i = s; i < e; ++i) {
        f32x2 f = fp8x2_f32_lo((unsigned int)h[(size_t)i * H_F + c]);
        sum += f.x;
    }
    atomicAdd(&pooled[g * H_F + c], sum);
}

// ------------------------------------------------------------------
// Fused MLP head (all fp32)
// ------------------------------------------------------------------
__global__ __launch_bounds__(256) void mlp_head_kernel(const float* __restrict__ pooled,
                                                       const int* __restrict__ gstart,
                                                       const float* __restrict__ Wm1,
                                                       const float* __restrict__ bm1,
                                                       const float* __restrict__ Wm2,
                                                       const float* __restrict__ bm2,
                                                       float* __restrict__ out) {
    __shared__ float p[H_F];
    __shared__ float h[H_F];
    __shared__ float lastv[OUT_F];
    __shared__ float stats[2];
    int g = blockIdx.x, j = threadIdx.x;
    int cnt = gstart[g + 1] - gstart[g];
    p[j] = pooled[g * H_F + j] / (float)max(cnt, 1);
    __syncthreads();
    float acc = bm1[j];
    for (int k = 0; k < H_F; ++k) acc += p[k] * Wm1[k * H_F + j];
    h[j] = fmaxf(acc, 0.f);
    __syncthreads();
    if (j < OUT_F) {
        float a = bm2[j];
        for (int k = 0; k < H_F; ++k) a += h[k] * Wm2[k * OUT_F + j];
        lastv[j] = a;
    }
    __syncthreads();
    if (j == 0) {
        float m = -1e30f;
        for (int o = 0; o < OUT_F; ++o) m = fmaxf(m, lastv[o]);
        float s = 0.f;
        for (int o = 0; o < OUT_F; ++o) s += expf(lastv[o] - m);
        stats[0] = m; stats[1] = logf(s);
    }
    __syncthreads();
    if (j < OUT_F) {
        float v = lastv[j];
        out[g * OUT_F + j] = v - stats[0] - stats[1];
        out[(size_t)N_G * OUT_F + g * OUT_F + j] = 1.f / (1.f + expf(-v));
        out[(size_t)2 * N_G * OUT_F + g * OUT_F + j] = v;
    }
}

// ------------------------------------------------------------------
extern "C" void kernel_launch(void* const* d_in, const int* in_sizes, int n_in,
                              void* d_out, int out_size, void* d_ws, size_t ws_size,
                              hipStream_t stream) {
    const float* x   = (const float*)d_in[0];
    const int* edge_index = (const int*)d_in[1];
    const int* batch = (const int*)d_in[3];
    const float* W0  = (const float*)d_in[4];
    const float* W1  = (const float*)d_in[5];
    const float* W2  = (const float*)d_in[6];
    const float* Wm1 = (const float*)d_in[7];
    const float* bm1 = (const float*)d_in[8];
    const float* Wm2 = (const float*)d_in[9];
    const float* bm2 = (const float*)d_in[10];
    float* out = (float*)d_out;

    char* ws = (char*)d_ws;
    size_t off = 0;
    auto alloc = [&](size_t bytes) -> void* {
        void* p = ws + off; off += (bytes + 255) & ~(size_t)255; return p;
    };
    u8* xb       = (u8*)alloc((size_t)N_PAD * IN_F);
    u8* bufA     = (u8*)alloc((size_t)N_PAD * H_F);
    u8* bufB     = (u8*)alloc((size_t)N_PAD * H_F);
    u8* t0       = (u8*)alloc((size_t)N_PAD * IN_F);
    u8* W0t      = (u8*)alloc((size_t)H_F * IN_F);
    u8* W1t      = (u8*)alloc((size_t)H_F * H_F);
    u8* W2t      = (u8*)alloc((size_t)H_F * H_F);
    float* dinv    = (float*)alloc((size_t)N_NODES * 4);
    int*   counts  = (int*)alloc((size_t)N_NODES * 4);
    int*   offsets = (int*)alloc((size_t)(N_NODES + 1) * 4);
    int*   rank    = (int*)alloc((size_t)N_EDGES * 4);
    unsigned int* csr_ew = (unsigned int*)alloc((size_t)CSR_CAP * 4);
    int*   csum    = (int*)alloc((size_t)256 * 4);
    int*   gstart  = (int*)alloc((size_t)(N_G + 1) * 4);
    float* pooled  = (float*)alloc((size_t)N_G * H_F * 4);

    const int* row = edge_index;
    const int* col = edge_index + N_EDGES;

    hipMemsetAsync(counts, 0, (size_t)N_NODES * 4, stream);

    histo_kernel<<<782, 256, 0, stream>>>(col, counts, rank);
    convert_kernel<<<CVT_GS, 256, 0, stream>>>(x, xb, W0, W0t, W1, W1t, W2, W2t,
                                               batch, gstart);
    chunk_reduce<<<NCHUNKS, 256, 0, stream>>>(counts, csum, pooled, N_NODES);
    scan_dinv_kernel<<<NCHUNKS, 256, 0, stream>>>(counts, csum, offsets, dinv,
                                                  csr_ew, N_NODES);
    fill_csr_kernel<<<3125, 256, 0, stream>>>(row, col, offsets, rank, dinv, csr_ew);

    dim3 gg(N_PAD / 128, H_F / 128);
    int agg_blocks = (N_NODES + 3) / 4;
    // layer 0: aggregate-first (linear ops commute), relu in GEMM epilogue
    aggregate128<<<agg_blocks, 256, 0, stream>>>(xb, dinv, offsets, csr_ew, t0);
    gemm_fp8<IN_F, true><<<gg, 256, 0, stream>>>(t0, W0t, bufA);
    // layer 1
    gemm_fp8<H_F, false><<<gg, 256, 0, stream>>>(bufA, W1t, bufB);
    aggregate256<<<agg_blocks, 256, 0, stream>>>(bufB, dinv, offsets, csr_ew, bufA);
    // layer 2
    gemm_fp8<H_F, false><<<gg, 256, 0, stream>>>(bufA, W2t, bufB);
    aggregate256<<<agg_blocks, 256, 0, stream>>>(bufB, dinv, offsets, csr_ew, bufA);

    dim3 pg(N_G, POOL_MAXCHUNKS);
    pool_part<<<pg, 256, 0, stream>>>(bufA, gstart, pooled);
    mlp_head_kernel<<<N_G, 256, 0, stream>>>(pooled, gstart, Wm1, bm1, Wm2, bm2, out);
}